// Round 2
// baseline (230.417 us; speedup 1.0000x reference)
//
#include <hip/hip_runtime.h>
#include <hip/hip_bf16.h>

// HistogramLoss: two [32,3,512,512] fp32 inputs, per-(B,C) 64-bin histogram
// over [0,1], normalized by row count (exactly 2^18), L1 mean of difference.
//
// R2: replace LDS-atomic histogram (80us, atomic-serialization bound, VALUBusy
// 6.5%) with ballot bit-slicing: BINS==64==wave size, so lane L of each wave
// accumulates the count of bin L in a register via 6 ballots + mask AND +
// popcount per 64 elements. Zero LDS traffic in the hot loop, zero atomics
// until the per-block epilogue. Still exact integer counting (absmax 0).

#define HW        262144      // 512*512 = 2^18
#define ROWS      96          // B*C per image
#define NBINS     64
#define BPR       16          // blocks per row
#define CHUNK     (HW / BPR)  // 16384 elements per block
#define THREADS   256
#define V4_PER_T  (CHUNK / 4 / THREADS)  // 16 float4 per thread
#define TOTAL_BC  (2 * ROWS * NBINS)     // 12288 hist entries

__device__ __forceinline__ unsigned popc64(unsigned long long m) {
    return __popcll(m);
}

__global__ __launch_bounds__(THREADS)
void hist_kernel(const float* __restrict__ fake,
                 const float* __restrict__ real,
                 unsigned int* __restrict__ ghist) {
    const int tid  = threadIdx.x;
    const int lane = tid & 63;
    const int wave = tid >> 6;

    const int b     = blockIdx.x;        // 0 .. 2*ROWS*BPR-1
    const int chunk = b % BPR;
    const int rowg  = b / BPR;           // 0..191: img*ROWS + row
    const float* src = (rowg < ROWS) ? fake : real;
    const int row    = (rowg < ROWS) ? rowg : (rowg - ROWS);

    const float4* __restrict__ p =
        (const float4*)(src + (size_t)row * HW + (size_t)chunk * CHUNK);

    // Per-lane XOR masks: xk = all-ones if lane bit k is 0, else 0.
    // Then lanes-matching-bin-L mask = AND_k (ballot_k ^ x_k) evaluated at lane L.
    const unsigned long long x0 = (lane & 1)  ? 0ull : ~0ull;
    const unsigned long long x1 = (lane & 2)  ? 0ull : ~0ull;
    const unsigned long long x2 = (lane & 4)  ? 0ull : ~0ull;
    const unsigned long long x3 = (lane & 8)  ? 0ull : ~0ull;
    const unsigned long long x4 = (lane & 16) ? 0ull : ~0ull;
    const unsigned long long x5 = (lane & 32) ? 0ull : ~0ull;

    unsigned cnt = 0;   // count of bin==lane among this wave's elements

#pragma unroll 4
    for (int i = 0; i < V4_PER_T; ++i) {
        float4 v = p[i * THREADS + tid];
        float c[4] = {v.x, v.y, v.z, v.w};
#pragma unroll
        for (int j = 0; j < 4; ++j) {
            int bi = min((int)(c[j] * 64.0f), 63);
            unsigned long long m0 = __ballot(bi & 1);
            unsigned long long m1 = __ballot(bi & 2);
            unsigned long long m2 = __ballot(bi & 4);
            unsigned long long m3 = __ballot(bi & 8);
            unsigned long long m4 = __ballot(bi & 16);
            unsigned long long m5 = __ballot(bi & 32);
            unsigned long long m = (m0 ^ x0) & (m1 ^ x1) & (m2 ^ x2)
                                 & (m3 ^ x3) & (m4 ^ x4) & (m5 ^ x5);
            cnt += popc64(m);
        }
    }

    // Combine the 4 waves' per-bin counts via plain LDS, one global atomic/bin.
    __shared__ unsigned int h[4][NBINS];
    h[wave][lane] = cnt;
    __syncthreads();
    if (tid < NBINS) {
        unsigned int s = h[0][tid] + h[1][tid] + h[2][tid] + h[3][tid];
        atomicAdd(&ghist[rowg * NBINS + tid], s);
    }
}

__global__ __launch_bounds__(THREADS)
void loss_kernel(const unsigned int* __restrict__ ghist, float* __restrict__ out) {
    const int tid = threadIdx.x;
    int acc = 0;
    // fake hist at [0, 6144), real hist at [6144, 12288)
    for (int i = tid; i < ROWS * NBINS; i += THREADS) {
        int cf = (int)ghist[i];
        int cr = (int)ghist[ROWS * NBINS + i];
        int d  = cf - cr;
        acc += (d < 0) ? -d : d;
    }
#pragma unroll
    for (int off = 32; off > 0; off >>= 1)
        acc += __shfl_down(acc, off, 64);
    __shared__ int wsum[4];
    if ((tid & 63) == 0) wsum[tid >> 6] = acc;
    __syncthreads();
    if (tid == 0) {
        int total = wsum[0] + wsum[1] + wsum[2] + wsum[3];
        out[0] = (float)((double)total / (262144.0 * (double)(ROWS * NBINS)));
    }
}

extern "C" void kernel_launch(void* const* d_in, const int* in_sizes, int n_in,
                              void* d_out, int out_size, void* d_ws, size_t ws_size,
                              hipStream_t stream) {
    const float* fake = (const float*)d_in[0];
    const float* real = (const float*)d_in[1];
    unsigned int* ghist = (unsigned int*)d_ws;   // 2*96*64 u32 = 49152 B
    float* out = (float*)d_out;

    hipMemsetAsync(ghist, 0, TOTAL_BC * sizeof(unsigned int), stream);

    dim3 grid(2 * ROWS * BPR);   // 3072 blocks
    hist_kernel<<<grid, THREADS, 0, stream>>>(fake, real, ghist);
    loss_kernel<<<1, THREADS, 0, stream>>>(ghist, out);
}

// Round 3
// 220.939 us; speedup vs baseline: 1.0429x; 1.0429x over previous
//
#include <hip/hip_runtime.h>
#include <hip/hip_bf16.h>

// HistogramLoss: two [32,3,512,512] fp32 inputs, per-(B,C) 64-bin histogram
// over [0,1], row-normalized (row count is exactly 2^18), L1 mean of diff.
//
// R3: hot loop uses per-THREAD private LDS byte counters (no atomics, no
// ballots). 256 thr x 68 B (64 bins + 4 B pad -> x17-word stride spreads
// bank bases over all 32 banks). Per element: 3 VALU + ds_read_u8/ds_write_b8.
// Epilogue: wave w lane L sums bin L over its 64 threads (conflict-free b32
// reads w/ broadcast), combine 4 waves, write per-block partials (no global
// atomics -> no memset node). Loss kernel widened to 1024 threads with
// coalesced unrolled loads. Exact integer counting throughout (absmax 0).

#define HW        262144             // 512*512 = 2^18
#define ROWS      96                 // B*C per image
#define NBINS     64
#define BPR       8                  // blocks per row
#define CHUNK     (HW / BPR)         // 32768 elements per block
#define THREADS   256
#define F4_ITERS  (CHUNK / 4 / THREADS)  // 32 float4 per thread (128 elems, fits u8)
#define NBLOCKS   (2 * ROWS * BPR)   // 1536
#define PITCH_W   17                 // u32 words per thread region (68 B)

__global__ __launch_bounds__(THREADS)
void hist_kernel(const float* __restrict__ fake,
                 const float* __restrict__ real,
                 unsigned int* __restrict__ partial) {
    __shared__ unsigned int priv[THREADS * PITCH_W];  // private byte counters
    __shared__ unsigned int comb[4][NBINS];

    const int tid  = threadIdx.x;
    const int lane = tid & 63;
    const int wv   = tid >> 6;

    // zero own region (no sync needed: regions are thread-private)
#pragma unroll
    for (int k = 0; k < PITCH_W; ++k) priv[tid * PITCH_W + k] = 0u;

    const int b     = blockIdx.x;          // 0 .. 1535
    const int chunk = b & (BPR - 1);
    const int rowg  = b >> 3;              // 0..191: img*ROWS + row
    const float* src = (rowg < ROWS) ? fake : real;
    const int row    = (rowg < ROWS) ? rowg : (rowg - ROWS);

    const float4* __restrict__ p =
        (const float4*)(src + (size_t)row * HW + (size_t)chunk * CHUNK);

    unsigned char* my = (unsigned char*)&priv[tid * PITCH_W];

#pragma unroll 4
    for (int i = 0; i < F4_ITERS; ++i) {
        float4 v = p[i * THREADS + tid];
        int b0 = min((int)(v.x * 64.0f), 63);
        int b1 = min((int)(v.y * 64.0f), 63);
        int b2 = min((int)(v.z * 64.0f), 63);
        int b3 = min((int)(v.w * 64.0f), 63);
        my[b0]++;
        my[b1]++;
        my[b2]++;
        my[b3]++;
    }
    __syncthreads();

    // wave wv, lane L: sum bin L over the wave's 64 threads.
    // word = t*17 + (L>>2): for fixed t, 4 lanes broadcast-share each word,
    // 16 distinct words -> conflict-free.
    const int cword = lane >> 2;
    const int shift = (lane & 3) * 8;
    unsigned cnt = 0;
#pragma unroll 8
    for (int t = 0; t < 64; ++t) {
        unsigned w32 = priv[(wv * 64 + t) * PITCH_W + cword];
        cnt += (w32 >> shift) & 0xffu;
    }
    comb[wv][lane] = cnt;
    __syncthreads();

    if (tid < NBINS) {
        unsigned s = comb[0][tid] + comb[1][tid] + comb[2][tid] + comb[3][tid];
        partial[(size_t)b * NBINS + tid] = s;   // plain coalesced store, no atomic
    }
}

__global__ __launch_bounds__(1024)
void loss_kernel(const unsigned int* __restrict__ partial,
                 float* __restrict__ out) {
    const int tid = threadIdx.x;
    int acc = 0;
    // 6144 (row,bin) pairs; 1024 threads -> 6 each; loads coalesced across tid.
#pragma unroll
    for (int q = 0; q < 6; ++q) {
        const int pIdx = q * 1024 + tid;     // 0..6143
        const int r  = pIdx >> 6;
        const int bb = pIdx & 63;
        unsigned cf = 0, cr = 0;
#pragma unroll
        for (int c = 0; c < BPR; ++c) {
            cf += partial[((r * BPR + c) * NBINS) + bb];
            cr += partial[(((ROWS + r) * BPR + c) * NBINS) + bb];
        }
        int d = (int)cf - (int)cr;
        acc += (d < 0) ? -d : d;
    }
#pragma unroll
    for (int off = 32; off > 0; off >>= 1)
        acc += __shfl_down(acc, off, 64);
    __shared__ int wsum[16];
    if ((tid & 63) == 0) wsum[tid >> 6] = acc;
    __syncthreads();
    if (tid == 0) {
        long long total = 0;
#pragma unroll
        for (int k = 0; k < 16; ++k) total += wsum[k];
        // loss = sum|cf-cr| / (2^18 * ROWS*NBINS)
        out[0] = (float)((double)total / (262144.0 * 6144.0));
    }
}

extern "C" void kernel_launch(void* const* d_in, const int* in_sizes, int n_in,
                              void* d_out, int out_size, void* d_ws, size_t ws_size,
                              hipStream_t stream) {
    const float* fake = (const float*)d_in[0];
    const float* real = (const float*)d_in[1];
    unsigned int* partial = (unsigned int*)d_ws;  // 1536*64 u32 = 393216 B
    float* out = (float*)d_out;

    hist_kernel<<<NBLOCKS, THREADS, 0, stream>>>(fake, real, partial);
    loss_kernel<<<1, 1024, 0, stream>>>(partial, out);
}